// Round 22
// baseline (166.641 us; speedup 1.0000x reference)
//
#include <hip/hip_runtime.h>
#include <hip/hip_fp16.h>
#include <cstdint>
#include <cstddef>

#define B_ 512
#define T_ 256
#define N_ 128
#define H_ 64
#define G_ 256  // 4H

typedef __attribute__((ext_vector_type(8))) short short8;
typedef __attribute__((ext_vector_type(4))) float f32x4;
typedef _Float16 half2_t __attribute__((ext_vector_type(2)));

static __device__ __forceinline__ float bf2f(unsigned short u) {
    union { unsigned int i; float f; } v;
    v.i = ((unsigned int)u) << 16;
    return v.f;
}
static __device__ __forceinline__ unsigned short f2bf(float f) {
    union { float f; unsigned int i; } v;
    v.f = f;
    unsigned int x = v.i;
    return (unsigned short)((x + 0x7fffu + ((x >> 16) & 1u)) >> 16);  // RNE
}
static __device__ __forceinline__ half2_t u2h2(unsigned int u) {
    union { unsigned int u; half2_t h; } v; v.u = u; return v.h;
}

// ---------------------------------------------------------------------------
// K0a: pack W_hh (f32 [4H][H]) -> wpack uint4 [4][8][64] (k_rnn lane order).
// ---------------------------------------------------------------------------
__global__ __launch_bounds__(256) void k_wpack(const float* __restrict__ W_hh,
                                               uint4* __restrict__ wpack) {
    int idx = blockIdx.x * 256 + threadIdx.x;   // 2048 entries
    if (idx >= 2048) return;
    int g = idx >> 9, q = (idx >> 6) & 7, j = idx & 63;
    const float* src = W_hh + ((size_t)(g * H_ + j)) * H_ + q * 8;
    float4 a = *(const float4*)(src);
    float4 b = *(const float4*)(src + 4);
    union { uint4 u; half2_t h[4]; } pk;
    pk.h[0] = (half2_t){(_Float16)a.x, (_Float16)a.y};
    pk.h[1] = (half2_t){(_Float16)a.z, (_Float16)a.w};
    pk.h[2] = (half2_t){(_Float16)b.x, (_Float16)b.y};
    pk.h[3] = (half2_t){(_Float16)b.z, (_Float16)b.w};
    wpack[idx] = pk.u;
}

// ---------------------------------------------------------------------------
// K0b: pack W_ih -> bf16 MFMA B-fragments, per-lane order (4096 entries).
// ---------------------------------------------------------------------------
__global__ __launch_bounds__(256) void k_wpackIH(const float* __restrict__ W_ih,
                                                 uint4* __restrict__ wp) {
    int idx = blockIdx.x * 256 + threadIdx.x;   // 4096 entries x 16B = 64 KB
    if (idx >= 4096) return;
    int lane = idx & 63;
    int rest = idx >> 6;            // w*16 + nt*4 + kc, 0..63
    int kc = rest & 3, nt = (rest >> 2) & 3, w = rest >> 4;
    int row = w * 64 + nt * 16 + (lane & 15);
    int kb  = kc * 32 + (lane >> 4) * 8;
    const float* src = W_ih + (size_t)row * N_ + kb;
    union { uint4 u; unsigned short s[8]; } pk;
    #pragma unroll
    for (int e = 0; e < 8; ++e) pk.s[e] = f2bf(src[e]);
    wp[idx] = pk.u;
}

// ---------------------------------------------------------------------------
// K1+K2: attention + weighting + GEMM (round-20 verified: ~38us, unchanged).
// ---------------------------------------------------------------------------
__global__ __attribute__((amdgpu_flat_work_group_size(256, 256)))
__attribute__((amdgpu_waves_per_eu(2, 2)))
void k_awgemm2(const float* __restrict__ x,
               const float* __restrict__ attn_w,
               const uint4* __restrict__ wih,
               const float* __restrict__ b_ih,
               const float* __restrict__ b_hh,
               float* __restrict__ iw,
               _Float16* __restrict__ gatesx) {
    __shared__ __align__(16) unsigned short Xl[T_][136];  // bf16 x / wx, padded
    __shared__ float red2[8][128];
    __shared__ float bias[G_];
    __shared__ float aw_s[T_];
    __shared__ float a_s[N_];
    __shared__ float wred[4];
    const int tid = threadIdx.x;
    const int b = blockIdx.x;
    const int lane = tid & 63;
    const int w = tid >> 6;

    uint4 bfw[4][4];   // [nt][kc]
    #pragma unroll
    for (int nt = 0; nt < 4; ++nt) {
        #pragma unroll
        for (int kc = 0; kc < 4; ++kc) {
            unsigned voff = (unsigned)((((w * 4 + nt) * 4 + kc) * 64 + lane) << 4);
            asm volatile("global_load_dwordx4 %0, %1, %2"
                         : "=v"(bfw[nt][kc]) : "v"(voff), "s"(wih) : "memory");
        }
    }
    asm volatile("s_waitcnt vmcnt(0)" ::: "memory");

    bias[tid] = b_ih[tid] + b_hh[tid];
    aw_s[tid] = attn_w[2 * H_ + tid];
    __syncthreads();

    const int n0 = (tid & 31) << 2;
    const int tg = tid >> 5;
    const float* xb = x + (size_t)b * (T_ * N_);
    {
        float p0 = 0.f, p1 = 0.f, p2 = 0.f, p3 = 0.f;
        for (int t = tg; t < T_; t += 8) {
            float4 v = *(const float4*)(xb + t * N_ + n0);
            float wt = aw_s[t];
            p0 += v.x * wt; p1 += v.y * wt; p2 += v.z * wt; p3 += v.w * wt;
            Xl[t][n0 + 0] = f2bf(v.x); Xl[t][n0 + 1] = f2bf(v.y);
            Xl[t][n0 + 2] = f2bf(v.z); Xl[t][n0 + 3] = f2bf(v.w);
        }
        red2[tg][n0 + 0] = p0; red2[tg][n0 + 1] = p1;
        red2[tg][n0 + 2] = p2; red2[tg][n0 + 3] = p3;
    }
    __syncthreads();
    {
        float s = 0.f;
        if (tid < 128) {
            #pragma unroll
            for (int g = 0; g < 8; ++g) s += red2[g][tid];
        }
        float m = (tid < 128) ? s : -1e30f;
        #pragma unroll
        for (int d = 1; d < 64; d <<= 1) m = fmaxf(m, __shfl_xor(m, d));
        if ((tid & 63) == 0) wred[tid >> 6] = m;
        __syncthreads();
        m = fmaxf(wred[0], wred[1]);
        __syncthreads();
        float e = (tid < 128) ? __expf(s - m) : 0.f;
        float z = e;
        #pragma unroll
        for (int d = 1; d < 64; d <<= 1) z += __shfl_xor(z, d);
        if ((tid & 63) == 0) wred[tid >> 6] = z;
        __syncthreads();
        z = wred[0] + wred[1];
        if (tid < 128) a_s[tid] = e / z;
    }
    __syncthreads();

    const int lr = lane & 15;
    const int lk = (lane >> 4) << 3;
    const int gc0 = w << 6;
    const int orow = (lane >> 4) << 2;

    for (int st = 0; st < 8; ++st) {
        const int r0g = b * T_ + st * 32;
        for (int q = tid; q < 32 * 32; q += 256) {
            int r = q >> 5, c4 = (q & 31) << 2;
            int row = st * 32 + r;
            ushort4 xv = *(const ushort4*)(&Xl[row][c4]);
            float4 wv4;
            wv4.x = a_s[c4 + 0] * bf2f(xv.x); wv4.y = a_s[c4 + 1] * bf2f(xv.y);
            wv4.z = a_s[c4 + 2] * bf2f(xv.z); wv4.w = a_s[c4 + 3] * bf2f(xv.w);
            *(float4*)(iw + (size_t)(r0g + r) * N_ + c4) = wv4;   // output 0
            Xl[row][c4 + 0] = f2bf(wv4.x); Xl[row][c4 + 1] = f2bf(wv4.y);
            Xl[row][c4 + 2] = f2bf(wv4.z); Xl[row][c4 + 3] = f2bf(wv4.w);
        }
        __syncthreads();

        f32x4 acc[2][4];
        #pragma unroll
        for (int mt = 0; mt < 2; ++mt)
            #pragma unroll
            for (int nt = 0; nt < 4; ++nt)
                acc[mt][nt] = (f32x4){0.f, 0.f, 0.f, 0.f};

        #pragma unroll
        for (int kc = 0; kc < 4; ++kc) {
            short8 af0 = *(const short8*)(&Xl[st * 32 + lr][kc * 32 + lk]);
            short8 af1 = *(const short8*)(&Xl[st * 32 + 16 + lr][kc * 32 + lk]);
            #pragma unroll
            for (int nt = 0; nt < 4; ++nt) {
                short8 bfv = *(const short8*)(&bfw[nt][kc]);
                acc[0][nt] = __builtin_amdgcn_mfma_f32_16x16x32_bf16(af0, bfv, acc[0][nt], 0, 0, 0);
                acc[1][nt] = __builtin_amdgcn_mfma_f32_16x16x32_bf16(af1, bfv, acc[1][nt], 0, 0, 0);
            }
        }
        #pragma unroll
        for (int mt = 0; mt < 2; ++mt) {
            #pragma unroll
            for (int nt = 0; nt < 4; ++nt) {
                int col = gc0 + nt * 16 + lr;
                float bs = bias[col];
                int cell = col & 63, qg = col >> 6;
                #pragma unroll
                for (int rg = 0; rg < 4; ++rg) {
                    int rr = r0g + mt * 16 + orow + rg;
                    gatesx[((size_t)rr * H_ + cell) * 4 + qg] =
                        (_Float16)(acc[mt][nt][rg] + bs);
                }
            }
        }
    }
}

// ---------------------------------------------------------------------------
// K3: LSTM recurrence — k_rnn17 (119.7us) with the last removable per-step
// instructions deleted (inst-count model: each inst ~ 4-6cy of wall):
//  1. peeled tail: main loop prefetches unconditionally (no clamp cmp/sel),
//     final 2 steps skip prefetch.
//  2. q=0 fdot2s unrolled with acc = gate f32 (e=0) or inline 0.0 (e=1..3):
//     kills 12 v_mov zero-inits per step.
//  3. walking gate pointer (gp += G_) instead of t*G_ address mul.
// ---------------------------------------------------------------------------
__global__ __attribute__((amdgpu_flat_work_group_size(64, 64)))
__attribute__((amdgpu_waves_per_eu(1, 1)))
void k_rnn18(const _Float16* __restrict__ gatesx,
             const uint4* __restrict__ wpack,
             float* __restrict__ enc) {
    __shared__ __align__(16) _Float16 hs[H_];   // h_t (f16), 128 B
    const int j = threadIdx.x;   // cell index
    const int b = blockIdx.x;

    uint4 wv[4][8];
    #pragma unroll
    for (int g = 0; g < 4; ++g) {
        #pragma unroll
        for (int q = 0; q < 8; ++q) {
            unsigned voff = (unsigned)((((g << 3) + q) * 64 + j) << 4);
            asm volatile("global_load_dwordx4 %0, %1, %2"
                         : "=v"(wv[g][q]) : "v"(voff), "s"(wpack) : "memory");
        }
    }
    asm volatile("s_waitcnt vmcnt(0)" ::: "memory");

    hs[j] = (_Float16)0.f;     // h_{-1} = 0 (single wave: DS in-order)
    float c = 0.f;

    const _Float16* gx = gatesx + ((size_t)b * T_ * H_ + j) * 4;
    float* ep = enc + (size_t)b * T_ * H_ + j;

    uint2 gA = *(const uint2*)(gx);            // t = 0
    uint2 gB = *(const uint2*)(gx + G_);       // t = 1
    const _Float16* gp = gx + 2 * (size_t)G_;  // next load address (t = 2)

#define SIG(x)  (__builtin_amdgcn_rcpf(1.f + __expf(-(x))))
#define TANH(x) (1.f - 2.f * __builtin_amdgcn_rcpf(__expf(2.f * (x)) + 1.f))
#define FD(W, H2, A) __builtin_amdgcn_fdot2((W), (H2), (A), false)

// DO_PF: 1 = reload GREG from *gp and advance gp (main loop); 0 = no prefetch.
#define STEP(GREG, DO_PF)                                                   \
    {                                                                       \
        half2_t gif = u2h2(GREG.x), ggo = u2h2(GREG.y);                     \
        float g0f = (float)gif.x, g1f = (float)gif.y;                       \
        float g2f = (float)ggo.x, g3f = (float)ggo.y;                       \
        if (DO_PF) { GREG = *(const uint2*)gp; gp += G_; }                  \
        const uint4* hv4 = (const uint4*)hs;                                \
        uint4 ch = hv4[0];                                                  \
        /* q = 0 unrolled: accs seeded from gates / inline 0 (no movs) */   \
        float pa00 = FD(u2h2(wv[0][0].x), u2h2(ch.x), g0f);                 \
        float pa10 = FD(u2h2(wv[1][0].x), u2h2(ch.x), g1f);                 \
        float pa20 = FD(u2h2(wv[2][0].x), u2h2(ch.x), g2f);                 \
        float pa30 = FD(u2h2(wv[3][0].x), u2h2(ch.x), g3f);                 \
        float pa01 = FD(u2h2(wv[0][0].y), u2h2(ch.y), 0.f);                 \
        float pa11 = FD(u2h2(wv[1][0].y), u2h2(ch.y), 0.f);                 \
        float pa21 = FD(u2h2(wv[2][0].y), u2h2(ch.y), 0.f);                 \
        float pa31 = FD(u2h2(wv[3][0].y), u2h2(ch.y), 0.f);                 \
        float pa02 = FD(u2h2(wv[0][0].z), u2h2(ch.z), 0.f);                 \
        float pa12 = FD(u2h2(wv[1][0].z), u2h2(ch.z), 0.f);                 \
        float pa22 = FD(u2h2(wv[2][0].z), u2h2(ch.z), 0.f);                 \
        float pa32 = FD(u2h2(wv[3][0].z), u2h2(ch.z), 0.f);                 \
        float pa03 = FD(u2h2(wv[0][0].w), u2h2(ch.w), 0.f);                 \
        float pa13 = FD(u2h2(wv[1][0].w), u2h2(ch.w), 0.f);                 \
        float pa23 = FD(u2h2(wv[2][0].w), u2h2(ch.w), 0.f);                 \
        float pa33 = FD(u2h2(wv[3][0].w), u2h2(ch.w), 0.f);                 \
        _Pragma("unroll")                                                   \
        for (int q = 1; q < 8; ++q) {                                       \
            uint4 cq = hv4[q];                                              \
            pa00 = FD(u2h2(wv[0][q].x), u2h2(cq.x), pa00);                  \
            pa10 = FD(u2h2(wv[1][q].x), u2h2(cq.x), pa10);                  \
            pa20 = FD(u2h2(wv[2][q].x), u2h2(cq.x), pa20);                  \
            pa30 = FD(u2h2(wv[3][q].x), u2h2(cq.x), pa30);                  \
            pa01 = FD(u2h2(wv[0][q].y), u2h2(cq.y), pa01);                  \
            pa11 = FD(u2h2(wv[1][q].y), u2h2(cq.y), pa11);                  \
            pa21 = FD(u2h2(wv[2][q].y), u2h2(cq.y), pa21);                  \
            pa31 = FD(u2h2(wv[3][q].y), u2h2(cq.y), pa31);                  \
            pa02 = FD(u2h2(wv[0][q].z), u2h2(cq.z), pa02);                  \
            pa12 = FD(u2h2(wv[1][q].z), u2h2(cq.z), pa12);                  \
            pa22 = FD(u2h2(wv[2][q].z), u2h2(cq.z), pa22);                  \
            pa32 = FD(u2h2(wv[3][q].z), u2h2(cq.z), pa32);                  \
            pa03 = FD(u2h2(wv[0][q].w), u2h2(cq.w), pa03);                  \
            pa13 = FD(u2h2(wv[1][q].w), u2h2(cq.w), pa13);                  \
            pa23 = FD(u2h2(wv[2][q].w), u2h2(cq.w), pa23);                  \
            pa33 = FD(u2h2(wv[3][q].w), u2h2(cq.w), pa33);                  \
        }                                                                   \
        float a0 = (pa00 + pa01) + (pa02 + pa03);                           \
        float a1 = (pa10 + pa11) + (pa12 + pa13);                           \
        float a2 = (pa20 + pa21) + (pa22 + pa23);                           \
        float a3 = (pa30 + pa31) + (pa32 + pa33);                           \
        float si = SIG(a0);                                                 \
        float sf = SIG(a1);                                                 \
        float tg = TANH(a2);                                                \
        float so = SIG(a3);                                                 \
        c = sf * c + si * tg;                                               \
        float tc = TANH(c);                                                 \
        float h = so * tc;                                                  \
        hs[j] = (_Float16)h;      /* in-order DS: visible to next step */   \
        *ep = h;                                                            \
        ep += H_;                                                           \
    }

    // main loop: t = 0..252 step 2 (steps 0..253; prefetches reach t+3 <= 255)
    for (int t = 0; t + 3 < T_; t += 2) {
        STEP(gA, 1);
        STEP(gB, 1);
    }
    // peeled final steps (t = 254, 255): no prefetch, no clamp needed
    STEP(gA, 0);
    STEP(gB, 0);
#undef STEP
#undef FD
#undef SIG
#undef TANH
}

extern "C" void kernel_launch(void* const* d_in, const int* in_sizes, int n_in,
                              void* d_out, int out_size, void* d_ws, size_t ws_size,
                              hipStream_t stream) {
    if (n_in < 7 || in_sizes[0] != B_ * T_ * N_) return;

    const float* x    = (const float*)d_in[0];
    const float* aw   = (const float*)d_in[1];
    // d_in[2] (attn_b) provably cancels in the softmax — unused.
    const float* W_ih = (const float*)d_in[3];
    const float* W_hh = (const float*)d_in[4];
    const float* b_ih = (const float*)d_in[5];
    const float* b_hh = (const float*)d_in[6];

    float* iwp = (float*)d_out;                          // (B,T,N) f32
    float* enc = (float*)d_out + (size_t)B_ * T_ * N_;   // (B,T,H) f32

    size_t gx_bytes = (size_t)B_ * T_ * G_ * sizeof(_Float16);   // 33.5 MB
    _Float16* gatesx = (_Float16*)d_ws;
    uint4* wpack = (uint4*)((char*)d_ws + gx_bytes);             // 32 KB
    uint4* wih   = wpack + 2048;                                 // 64 KB
    size_t need = gx_bytes + 2048 * sizeof(uint4) + 4096 * sizeof(uint4);
    if (ws_size < need) return;  // fail loudly rather than corrupt

    hipLaunchKernelGGL(k_wpack, dim3(8), dim3(256), 0, stream, W_hh, wpack);
    hipLaunchKernelGGL(k_wpackIH, dim3(16), dim3(256), 0, stream, W_ih, wih);
    hipLaunchKernelGGL(k_awgemm2, dim3(B_), dim3(256), 0, stream,
                       x, aw, wih, b_ih, b_hh, iwp, gatesx);
    hipLaunchKernelGGL(k_rnn18, dim3(B_), dim3(64), 0, stream,
                       gatesx, wpack, enc);
}